// Round 3
// baseline (193.516 us; speedup 1.0000x reference)
//
#include <hip/hip_runtime.h>
#include <hip/hip_bf16.h>
#include <cmath>

#define B_   2
#define S_   2048
#define D_   768
#define H_   12
#define HD_  64
#define WIN_ 64

typedef __bf16 bf16x8 __attribute__((ext_vector_type(8)));
typedef __bf16 bf16x4 __attribute__((ext_vector_type(4)));
typedef float  f32x4  __attribute__((ext_vector_type(4)));
typedef unsigned int u32;

__device__ __forceinline__ void async_ld16(const void* g, void* l) {
    __builtin_amdgcn_global_load_lds(
        (__attribute__((address_space(1))) void*)(size_t)g,
        (__attribute__((address_space(3))) void*)(u32)(size_t)l,
        16, 0, 0);
}

// ---------------------------------------------------------------------------
// fp32 -> bf16 convert for hs / Wqkv / Wo (one pass)
// ---------------------------------------------------------------------------
#define NHS (B_ * S_ * D_)        // 3145728
#define NWQ (3 * D_ * D_)         // 1769472
#define NWO (D_ * D_)             //  589824

__global__ __launch_bounds__(256) void to_bf16_3(const float* __restrict__ a,
                                                 const float* __restrict__ b,
                                                 const float* __restrict__ c,
                                                 __bf16* __restrict__ oa,
                                                 __bf16* __restrict__ ob,
                                                 __bf16* __restrict__ oc) {
    const int NA = NHS / 4, NB = NWQ / 4;
    int v = blockIdx.x * 256 + threadIdx.x;
    const float* src; __bf16* dst; int idx;
    if (v < NA)           { src = a; dst = oa; idx = v; }
    else if (v < NA + NB) { src = b; dst = ob; idx = v - NA; }
    else                  { src = c; dst = oc; idx = v - NA - NB; }
    float4 x = ((const float4*)src)[idx];
    bf16x4 y = { (__bf16)x.x, (__bf16)x.y, (__bf16)x.z, (__bf16)x.w };
    *(bf16x4*)(dst + (size_t)idx * 4) = y;
}

// ---------------------------------------------------------------------------
// GEMM, round-14: REGISTER-direct fragments, NO LDS in the K-loop.
// Rounds 0-2 never overlapped loads with MFMA: LLVM treats global_load_lds
// as LDS-DMA and inserts its own vmcnt(0) before any possibly-aliasing
// ds_read (runtime buf index => may-alias => full drain every iteration).
// Fix: the LDS bounce was semantically a no-op (frag = A[m0+t*16+fr][k0+
// fq*8..+7], a contiguous 16-B global load), so load fragments straight
// into named double-buffered VGPRs (a0/b0, a1/b1, unroll-2, no runtime
// indexing).  Compiler emits precise counted vmcnt for register loads.
// Each wave owns a full 64x64 tile over all K (24 iters).  4 waves/block,
// wave w takes n-tile (id>>6)*4+w; m fastest (XCD A-panel partitioning).
// LDS only for the per-wave coalescing epilogue bounce (plain ds ops).
// MODE 0: fp32 C.  MODE 1: fused RoPE -> qkv bf16 (n<1536); v -> vt bf16^T.
// ---------------------------------------------------------------------------
template <int MODE>
__global__ __launch_bounds__(256, 3) void gemm_r(const __bf16* __restrict__ A,
                                                 const __bf16* __restrict__ Bw,
                                                 float* __restrict__ C,
                                                 __bf16* __restrict__ qkv,
                                                 __bf16* __restrict__ vt,
                                                 const int* __restrict__ pos,
                                                 int M, int N, int K) {
    __shared__ __attribute__((aligned(16))) char esmem[4][8704];

    const int tid  = threadIdx.x;
    const int w    = tid >> 6;
    const int lane = tid & 63;
    const int id = blockIdx.x;
    const int m0 = (id & 63) << 6;              // m fastest: XCD partitioning
    const int n0 = (((id >> 6) << 2) + w) << 6; // per-wave n panel
    const int fr = lane & 15, fq = lane >> 4;

    const __bf16* Ap = A  + (size_t)(m0 + fr) * K + fq * 8;
    const __bf16* Bp = Bw + (size_t)(n0 + fr) * K + fq * 8;
    const size_t rstep = (size_t)16 * K;        // 16 rows

    f32x4 acc[4][4] = {};
    bf16x8 a0[4], b0[4], a1[4], b1[4];

    auto LD = [&](bf16x8 (&ar)[4], bf16x8 (&br)[4], int kk) {
        const int ko = kk << 5;                 // elements
        #pragma unroll
        for (int t = 0; t < 4; ++t) {
            ar[t] = *(const bf16x8*)(Ap + (size_t)t * rstep + ko);
            br[t] = *(const bf16x8*)(Bp + (size_t)t * rstep + ko);
        }
    };
    auto MM = [&](const bf16x8 (&ar)[4], const bf16x8 (&br)[4]) {
        #pragma unroll
        for (int ti = 0; ti < 4; ++ti)
            #pragma unroll
            for (int tj = 0; tj < 4; ++tj)
                acc[ti][tj] = __builtin_amdgcn_mfma_f32_16x16x32_bf16(
                    ar[ti], br[tj], acc[ti][tj], 0, 0, 0);
    };

    const int nkw = K >> 5;                     // 24
    LD(a0, b0, 0);
    for (int kk = 0; kk + 2 < nkw; kk += 2) {   // 11 iters, tiles 0..21
        LD(a1, b1, kk + 1);                     // prefetch odd tile
        MM(a0, b0);
        LD(a0, b0, kk + 2);                     // prefetch even tile
        MM(a1, b1);
    }
    LD(a1, b1, nkw - 1);
    MM(a0, b0);                                 // tile nkw-2
    MM(a1, b1);                                 // tile nkw-1

    // ---- per-wave epilogue, coalesced via private LDS bounce ----
    if (MODE == 0) {
        // fp32 [32][65] bounce, two 32-row halves
        float* eL = (float*)esmem[w];
        #pragma unroll
        for (int half = 0; half < 2; ++half) {
            #pragma unroll
            for (int ti = 0; ti < 2; ++ti)
                #pragma unroll
                for (int tj = 0; tj < 4; ++tj)
                    #pragma unroll
                    for (int r = 0; r < 4; ++r)
                        eL[(ti * 16 + fq * 4 + r) * 65 + tj * 16 + fr] =
                            acc[half * 2 + ti][tj][r];
            #pragma unroll
            for (int p = 0; p < 8; ++p) {
                const int rc = p * 4 + (lane >> 4), ch = lane & 15;
                f32x4 vv = *(const f32x4*)(eL + rc * 65 + ch * 4);
                *(f32x4*)(C + (size_t)(m0 + half * 32 + rc) * N + n0 + ch * 4) = vv;
            }
        }
    } else if (n0 < 2 * D_) {
        // fused RoPE on fp32 acc, then bf16 coalesced store
        const float invf0 = __powf(10000.0f, -(float)fr * (1.0f / 32.0f));
        const float invf1 = __powf(10000.0f, -(float)(16 + fr) * (1.0f / 32.0f));
        #pragma unroll
        for (int ti = 0; ti < 4; ++ti)
            #pragma unroll
            for (int r = 0; r < 4; ++r) {
                const int row = m0 + ti * 16 + fq * 4 + r;
                const float p = (float)pos[row];
                float s0, c0, s1, c1;
                __sincosf(p * invf0, &s0, &c0);
                __sincosf(p * invf1, &s1, &c1);
                const float x0 = acc[ti][0][r], x1 = acc[ti][2][r];
                acc[ti][0][r] = x0 * c0 - x1 * s0;
                acc[ti][2][r] = x1 * c0 + x0 * s0;
                const float y0 = acc[ti][1][r], y1 = acc[ti][3][r];
                acc[ti][1][r] = y0 * c1 - y1 * s1;
                acc[ti][3][r] = y1 * c1 + y0 * s1;
            }
        __bf16* eL = (__bf16*)esmem[w];           // [64][68] bf16
        #pragma unroll
        for (int ti = 0; ti < 4; ++ti)
            #pragma unroll
            for (int tj = 0; tj < 4; ++tj)
                #pragma unroll
                for (int r = 0; r < 4; ++r)
                    eL[(ti * 16 + fq * 4 + r) * 68 + tj * 16 + fr] = (__bf16)acc[ti][tj][r];
        #pragma unroll
        for (int p = 0; p < 8; ++p) {
            const int rq = p * 8 + (lane >> 3), ch = lane & 7;
            bf16x8 vv = *(const bf16x8*)(eL + rq * 68 + ch * 8);
            *(bf16x8*)(qkv + (size_t)(m0 + rq) * (2 * D_) + n0 + ch * 8) = vv;
        }
    } else {
        // v -> vt[b][h][d][token], transposed in LDS, coalesced 128-B rows
        const int h = (n0 - 2 * D_) >> 6;
        const int bb = m0 >> 11, t0 = m0 & (S_ - 1);
        __bf16* eL = (__bf16*)esmem[w];           // [64 d][68 tok] bf16
        #pragma unroll
        for (int ti = 0; ti < 4; ++ti)
            #pragma unroll
            for (int tj = 0; tj < 4; ++tj)
                #pragma unroll
                for (int r = 0; r < 4; ++r)
                    eL[(tj * 16 + fr) * 68 + ti * 16 + fq * 4 + r] = (__bf16)acc[ti][tj][r];
        const size_t vb = (size_t)((bb * H_ + h) * HD_) * S_ + t0;
        #pragma unroll
        for (int p = 0; p < 8; ++p) {
            const int d = p * 8 + (lane >> 3), ch = lane & 7;
            bf16x8 vv = *(const bf16x8*)(eL + d * 68 + ch * 8);
            *(bf16x8*)(vt + vb + (size_t)d * S_ + ch * 8) = vv;
        }
    }
}

// ---------------------------------------------------------------------------
// MFMA banded attention.  Block = 64 queries x (head, batch), 4 waves.
// LDS (48 KB): Ks [2][192][32] (24 KB, overlaid by P), Vts [6][64][32] (24 KB).
// Q frags direct from global.  O store bounced through LDS (coalesced 128-B).
// ---------------------------------------------------------------------------
__global__ __launch_bounds__(256) void attn_mfma(const __bf16* __restrict__ qkv,
                                                 const __bf16* __restrict__ vt,
                                                 __bf16* __restrict__ outb) {
    __shared__ __attribute__((aligned(16))) __bf16 smem[24576];  // 48 KB
    __bf16* Ks  = smem;
    __bf16* Vts = smem + 12288;

    const int i0  = blockIdx.x * 64;
    const int h   = blockIdx.y;
    const int b   = blockIdx.z;
    const int tid = threadIdx.x;
    const int w = tid >> 6, lane = tid & 63;
    const int fr = lane & 15, fq = lane >> 4;
    const int wq0 = w * 16;

    #pragma unroll
    for (int i = 0; i < 6; ++i) {
        int c = i * 256 + tid;
        int ks = (i >= 3);
        int rem = c - ks * 768;
        int cc = rem & 3, row = rem >> 2;
        int j = i0 - 64 + row; j = min(max(j, 0), S_ - 1);   // clamped; masked later
        async_ld16(qkv + ((size_t)b * S_ + j) * (2 * D_) + D_ + h * HD_ + ks * 32 + cc * 8,
                   Ks + c * 8);
    }
    const size_t vbase = (size_t)((b * H_ + h) * HD_) * S_;
    #pragma unroll
    for (int i = 0; i < 6; ++i) {
        int c = i * 256 + tid;
        int ks = c >> 8, rem = c & 255, d = rem >> 2, cc = rem & 3;
        int key = i0 - 64 + ks * 32 + cc * 8;
        key = min(max(key, 0), S_ - 8);                      // clamped; masked later
        async_ld16(vt + vbase + (size_t)d * S_ + key, Vts + c * 8);
    }

    const size_t qrow = ((size_t)b * S_ + i0 + wq0 + fr) * (2 * D_) + h * HD_;
    bf16x8 aq[2];
    aq[0] = *(const bf16x8*)(qkv + qrow + fq * 8);
    aq[1] = *(const bf16x8*)(qkv + qrow + 32 + fq * 8);

    __syncthreads();

    f32x4 sc[12] = {};
    #pragma unroll
    for (int nt = 0; nt < 12; ++nt) {
        #pragma unroll
        for (int ks = 0; ks < 2; ++ks) {
            bf16x8 bk = *(const bf16x8*)(Ks + (ks * 192 + nt * 16 + fr) * 32 + fq * 8);
            sc[nt] = __builtin_amdgcn_mfma_f32_16x16x32_bf16(aq[ks], bk, sc[nt], 0, 0, 0);
        }
    }

    float mx[4] = { -1e30f, -1e30f, -1e30f, -1e30f };
    #pragma unroll
    for (int nt = 0; nt < 12; ++nt) {
        const int jr = nt * 16 + fr;
        const int j  = i0 - 64 + jr;
        const bool jv = (j >= 0) && (j < S_);
        #pragma unroll
        for (int r = 0; r < 4; ++r) {
            const int ir = wq0 + fq * 4 + r + 64;
            const int dd = ir - jr;
            const bool v = jv && (dd <= WIN_) && (dd >= -WIN_);
            sc[nt][r] = v ? sc[nt][r] * 0.125f : -1e30f;
            mx[r] = fmaxf(mx[r], sc[nt][r]);
        }
    }
    #pragma unroll
    for (int r = 0; r < 4; ++r)
        #pragma unroll
        for (int off = 1; off < 16; off <<= 1)
            mx[r] = fmaxf(mx[r], __shfl_xor(mx[r], off, 64));

    float sm[4] = { 0.f, 0.f, 0.f, 0.f };
    #pragma unroll
    for (int nt = 0; nt < 12; ++nt)
        #pragma unroll
        for (int r = 0; r < 4; ++r) {
            float e = __expf(sc[nt][r] - mx[r]);
            sc[nt][r] = e;
            sm[r] += e;
        }
    #pragma unroll
    for (int r = 0; r < 4; ++r) {
        #pragma unroll
        for (int off = 1; off < 16; off <<= 1)
            sm[r] += __shfl_xor(sm[r], off, 64);
        sm[r] = 1.0f / sm[r];
    }

    __syncthreads();

    __bf16* Pw = Ks + w * 3072;
    #pragma unroll
    for (int nt = 0; nt < 12; ++nt) {
        const int ks = nt >> 1, kk = (nt & 1) * 16 + fr;
        #pragma unroll
        for (int r = 0; r < 4; ++r)
            Pw[(ks * 16 + fq * 4 + r) * 32 + kk] = (__bf16)(sc[nt][r] * sm[r]);
    }

    f32x4 oacc[4] = {};
    #pragma unroll
    for (int ks = 0; ks < 6; ++ks) {
        bf16x8 ap = *(const bf16x8*)(Pw + (ks * 16 + fr) * 32 + fq * 8);
        #pragma unroll
        for (int nt2 = 0; nt2 < 4; ++nt2) {
            bf16x8 bv = *(const bf16x8*)(Vts + (ks * 64 + nt2 * 16 + fr) * 32 + fq * 8);
            oacc[nt2] = __builtin_amdgcn_mfma_f32_16x16x32_bf16(ap, bv, oacc[nt2], 0, 0, 0);
        }
    }

    // O via per-wave LDS bounce (reuse Pw region) -> coalesced 128-B rows
    #pragma unroll
    for (int nt2 = 0; nt2 < 4; ++nt2)
        #pragma unroll
        for (int r = 0; r < 4; ++r)
            Pw[(fq * 4 + r) * 68 + nt2 * 16 + fr] = (__bf16)oacc[nt2][r];
    #pragma unroll
    for (int p = 0; p < 2; ++p) {
        const int q = p * 8 + (lane >> 3), ch = lane & 7;
        bf16x8 vv = *(const bf16x8*)(Pw + q * 68 + ch * 8);
        *(bf16x8*)(outb + ((size_t)b * S_ + i0 + wq0 + q) * D_ + h * HD_ + ch * 8) = vv;
    }
}

// ---------------------------------------------------------------------------
extern "C" void kernel_launch(void* const* d_in, const int* in_sizes, int n_in,
                              void* d_out, int out_size, void* d_ws, size_t ws_size,
                              hipStream_t stream) {
    const float* hs   = (const float*)d_in[0];
    const float* wqkv = (const float*)d_in[1];
    const float* wo   = (const float*)d_in[2];
    const int*   pos  = (const int*)d_in[4];
    float* out = (float*)d_out;

    __bf16* base    = (__bf16*)d_ws;
    __bf16* hs_bf   = base;                          // 3,145,728
    __bf16* wqkv_bf = hs_bf + NHS;                   // 1,769,472
    __bf16* wo_bf   = wqkv_bf + NWQ;                 //   589,824
    __bf16* qkv     = wo_bf + NWO;                   // 4096*1536
    __bf16* vt      = qkv + (size_t)(B_ * S_) * (2 * D_);   // 2*12*64*2048
    __bf16* attn_bf = vt + (size_t)B_ * H_ * HD_ * S_;      // 4096*768

    // 1) fp32 -> bf16
    to_bf16_3<<<(NHS + NWQ + NWO) / 1024, 256, 0, stream>>>(
        hs, wqkv, wo, hs_bf, wqkv_bf, wo_bf);

    // 2) qkv = hs @ Wqkv^T  (RoPE fused -> qkv bf16; v -> vt transposed)
    //    register-direct fragments, 2304 waves all resident
    gemm_r<1><<<dim3(64 * (3 * D_ / 256)), 256, 0, stream>>>(
        hs_bf, wqkv_bf, nullptr, qkv, vt, pos, B_ * S_, 3 * D_, D_);

    // 3) banded MFMA attention
    attn_mfma<<<dim3(S_ / 64, H_, B_), 256, 0, stream>>>(qkv, vt, attn_bf);

    // 4) out = attn @ Wo^T (fp32 out, coalesced epilogue)
    gemm_r<0><<<dim3(64 * (D_ / 256)), 256, 0, stream>>>(
        attn_bf, wo_bf, out, nullptr, nullptr, nullptr, B_ * S_, D_, D_);
}

// Round 4
// 190.573 us; speedup vs baseline: 1.0154x; 1.0154x over previous
//
#include <hip/hip_runtime.h>
#include <hip/hip_bf16.h>
#include <cmath>

#define B_   2
#define S_   2048
#define D_   768
#define H_   12
#define HD_  64
#define WIN_ 64

typedef __bf16 bf16x8 __attribute__((ext_vector_type(8)));
typedef __bf16 bf16x4 __attribute__((ext_vector_type(4)));
typedef float  f32x4  __attribute__((ext_vector_type(4)));
typedef unsigned int u32;

__device__ __forceinline__ void async_ld16(const void* g, void* l) {
    __builtin_amdgcn_global_load_lds(
        (__attribute__((address_space(1))) void*)(size_t)g,
        (__attribute__((address_space(3))) void*)(u32)(size_t)l,
        16, 0, 0);
}

// ---------------------------------------------------------------------------
// fp32 -> bf16 convert for hs / Wqkv / Wo (one pass)
// ---------------------------------------------------------------------------
#define NHS (B_ * S_ * D_)        // 3145728
#define NWQ (3 * D_ * D_)         // 1769472
#define NWO (D_ * D_)             //  589824

__global__ __launch_bounds__(256) void to_bf16_3(const float* __restrict__ a,
                                                 const float* __restrict__ b,
                                                 const float* __restrict__ c,
                                                 __bf16* __restrict__ oa,
                                                 __bf16* __restrict__ ob,
                                                 __bf16* __restrict__ oc) {
    const int NA = NHS / 4, NB = NWQ / 4;
    int v = blockIdx.x * 256 + threadIdx.x;
    const float* src; __bf16* dst; int idx;
    if (v < NA)           { src = a; dst = oa; idx = v; }
    else if (v < NA + NB) { src = b; dst = ob; idx = v - NA; }
    else                  { src = c; dst = oc; idx = v - NA - NB; }
    float4 x = ((const float4*)src)[idx];
    bf16x4 y = { (__bf16)x.x, (__bf16)x.y, (__bf16)x.z, (__bf16)x.w };
    *(bf16x4*)(dst + (size_t)idx * 4) = y;
}

// ---------------------------------------------------------------------------
// GEMM, round-15: register-direct fragments, scratch-free.
// Round-3 post-mortem: VGPR_Count=80 proved the lambda-ref-captured frag
// arrays were demoted to scratch (L2-contained round-trips, ~7200 cyc/iter,
// both gemms pinned at 72 us = one wave's serial path).  Fix: no lambdas;
// frag arrays at function scope, accessed ONLY in #pragma unroll loops with
// literal indices (same discipline that keeps acc[][] in AGPRs).  Depth-2
// prefetch in straight-line code.
// Each wave owns a full 64x64 tile over all K (24 iters).  4 waves/block,
// wave w takes n-tile (id>>6)*4+w; m fastest (XCD A-panel partitioning).
// LDS only for the per-wave coalescing epilogue bounce.
// MODE 0: fp32 C.  MODE 1: fused RoPE -> qkv bf16 (n<1536); v -> vt bf16^T.
// ---------------------------------------------------------------------------
#define LD_FRAGS(AR, BR, kk)                                                  \
    _Pragma("unroll")                                                         \
    for (int t_ = 0; t_ < 4; ++t_) {                                          \
        AR[t_] = *(const bf16x8*)(Ap + (size_t)t_ * rstep + ((kk) << 5));     \
        BR[t_] = *(const bf16x8*)(Bp + (size_t)t_ * rstep + ((kk) << 5));     \
    }

#define MM_FRAGS(AR, BR)                                                      \
    _Pragma("unroll")                                                         \
    for (int ti_ = 0; ti_ < 4; ++ti_)                                         \
        _Pragma("unroll")                                                     \
        for (int tj_ = 0; tj_ < 4; ++tj_)                                     \
            acc[ti_][tj_] = __builtin_amdgcn_mfma_f32_16x16x32_bf16(          \
                AR[ti_], BR[tj_], acc[ti_][tj_], 0, 0, 0);

template <int MODE>
__global__ __launch_bounds__(256, 3) void gemm_r(const __bf16* __restrict__ A,
                                                 const __bf16* __restrict__ Bw,
                                                 float* __restrict__ C,
                                                 __bf16* __restrict__ qkv,
                                                 __bf16* __restrict__ vt,
                                                 const int* __restrict__ pos,
                                                 int M, int N, int K) {
    __shared__ __attribute__((aligned(16))) char esmem[4][8704];

    const int tid  = threadIdx.x;
    const int w    = tid >> 6;
    const int lane = tid & 63;
    const int id = blockIdx.x;
    const int m0 = (id & 63) << 6;              // m fastest: XCD partitioning
    const int n0 = (((id >> 6) << 2) + w) << 6; // per-wave n panel
    const int fr = lane & 15, fq = lane >> 4;

    const __bf16* Ap = A  + (size_t)(m0 + fr) * K + fq * 8;
    const __bf16* Bp = Bw + (size_t)(n0 + fr) * K + fq * 8;
    const size_t rstep = (size_t)16 * K;        // 16 rows

    f32x4 acc[4][4] = {};
    bf16x8 A0[4], B0[4], A1[4], B1[4];

    const int nkw = K >> 5;                     // 24 (even)

    LD_FRAGS(A0, B0, 0)
    LD_FRAGS(A1, B1, 1)
    for (int kk = 0; kk < nkw - 2; kk += 2) {
        MM_FRAGS(A0, B0)
        LD_FRAGS(A0, B0, kk + 2)
        MM_FRAGS(A1, B1)
        LD_FRAGS(A1, B1, kk + 3)
    }
    MM_FRAGS(A0, B0)                            // tile nkw-2
    MM_FRAGS(A1, B1)                            // tile nkw-1

    // ---- per-wave epilogue, coalesced via private LDS bounce ----
    if (MODE == 0) {
        // fp32 [32][65] bounce, two 32-row halves
        float* eL = (float*)esmem[w];
        #pragma unroll
        for (int half = 0; half < 2; ++half) {
            #pragma unroll
            for (int ti = 0; ti < 2; ++ti)
                #pragma unroll
                for (int tj = 0; tj < 4; ++tj)
                    #pragma unroll
                    for (int r = 0; r < 4; ++r)
                        eL[(ti * 16 + fq * 4 + r) * 65 + tj * 16 + fr] =
                            acc[half * 2 + ti][tj][r];
            #pragma unroll
            for (int p = 0; p < 8; ++p) {
                const int rc = p * 4 + (lane >> 4), ch = lane & 15;
                f32x4 vv = *(const f32x4*)(eL + rc * 65 + ch * 4);
                *(f32x4*)(C + (size_t)(m0 + half * 32 + rc) * N + n0 + ch * 4) = vv;
            }
        }
    } else if (n0 < 2 * D_) {
        // fused RoPE on fp32 acc, then bf16 coalesced store
        const float invf0 = __powf(10000.0f, -(float)fr * (1.0f / 32.0f));
        const float invf1 = __powf(10000.0f, -(float)(16 + fr) * (1.0f / 32.0f));
        #pragma unroll
        for (int ti = 0; ti < 4; ++ti)
            #pragma unroll
            for (int r = 0; r < 4; ++r) {
                const int row = m0 + ti * 16 + fq * 4 + r;
                const float p = (float)pos[row];
                float s0, c0, s1, c1;
                __sincosf(p * invf0, &s0, &c0);
                __sincosf(p * invf1, &s1, &c1);
                const float x0 = acc[ti][0][r], x1 = acc[ti][2][r];
                acc[ti][0][r] = x0 * c0 - x1 * s0;
                acc[ti][2][r] = x1 * c0 + x0 * s0;
                const float y0 = acc[ti][1][r], y1 = acc[ti][3][r];
                acc[ti][1][r] = y0 * c1 - y1 * s1;
                acc[ti][3][r] = y1 * c1 + y0 * s1;
            }
        __bf16* eL = (__bf16*)esmem[w];           // [64][68] bf16
        #pragma unroll
        for (int ti = 0; ti < 4; ++ti)
            #pragma unroll
            for (int tj = 0; tj < 4; ++tj)
                #pragma unroll
                for (int r = 0; r < 4; ++r)
                    eL[(ti * 16 + fq * 4 + r) * 68 + tj * 16 + fr] = (__bf16)acc[ti][tj][r];
        #pragma unroll
        for (int p = 0; p < 8; ++p) {
            const int rq = p * 8 + (lane >> 3), ch = lane & 7;
            bf16x8 vv = *(const bf16x8*)(eL + rq * 68 + ch * 8);
            *(bf16x8*)(qkv + (size_t)(m0 + rq) * (2 * D_) + n0 + ch * 8) = vv;
        }
    } else {
        // v -> vt[b][h][d][token], transposed in LDS, coalesced 128-B rows
        const int h = (n0 - 2 * D_) >> 6;
        const int bb = m0 >> 11, t0 = m0 & (S_ - 1);
        __bf16* eL = (__bf16*)esmem[w];           // [64 d][68 tok] bf16
        #pragma unroll
        for (int ti = 0; ti < 4; ++ti)
            #pragma unroll
            for (int tj = 0; tj < 4; ++tj)
                #pragma unroll
                for (int r = 0; r < 4; ++r)
                    eL[(tj * 16 + fr) * 68 + ti * 16 + fq * 4 + r] = (__bf16)acc[ti][tj][r];
        const size_t vb = (size_t)((bb * H_ + h) * HD_) * S_ + t0;
        #pragma unroll
        for (int p = 0; p < 8; ++p) {
            const int d = p * 8 + (lane >> 3), ch = lane & 7;
            bf16x8 vv = *(const bf16x8*)(eL + d * 68 + ch * 8);
            *(bf16x8*)(vt + vb + (size_t)d * S_ + ch * 8) = vv;
        }
    }
}

// ---------------------------------------------------------------------------
// MFMA banded attention.  Block = 64 queries x (head, batch), 4 waves.
// LDS (48 KB): Ks [2][192][32] (24 KB, overlaid by P), Vts [6][64][32] (24 KB).
// Q frags direct from global.  O store bounced through LDS (coalesced 128-B).
// ---------------------------------------------------------------------------
__global__ __launch_bounds__(256) void attn_mfma(const __bf16* __restrict__ qkv,
                                                 const __bf16* __restrict__ vt,
                                                 __bf16* __restrict__ outb) {
    __shared__ __attribute__((aligned(16))) __bf16 smem[24576];  // 48 KB
    __bf16* Ks  = smem;
    __bf16* Vts = smem + 12288;

    const int i0  = blockIdx.x * 64;
    const int h   = blockIdx.y;
    const int b   = blockIdx.z;
    const int tid = threadIdx.x;
    const int w = tid >> 6, lane = tid & 63;
    const int fr = lane & 15, fq = lane >> 4;
    const int wq0 = w * 16;

    #pragma unroll
    for (int i = 0; i < 6; ++i) {
        int c = i * 256 + tid;
        int ks = (i >= 3);
        int rem = c - ks * 768;
        int cc = rem & 3, row = rem >> 2;
        int j = i0 - 64 + row; j = min(max(j, 0), S_ - 1);   // clamped; masked later
        async_ld16(qkv + ((size_t)b * S_ + j) * (2 * D_) + D_ + h * HD_ + ks * 32 + cc * 8,
                   Ks + c * 8);
    }
    const size_t vbase = (size_t)((b * H_ + h) * HD_) * S_;
    #pragma unroll
    for (int i = 0; i < 6; ++i) {
        int c = i * 256 + tid;
        int ks = c >> 8, rem = c & 255, d = rem >> 2, cc = rem & 3;
        int key = i0 - 64 + ks * 32 + cc * 8;
        key = min(max(key, 0), S_ - 8);                      // clamped; masked later
        async_ld16(vt + vbase + (size_t)d * S_ + key, Vts + c * 8);
    }

    const size_t qrow = ((size_t)b * S_ + i0 + wq0 + fr) * (2 * D_) + h * HD_;
    bf16x8 aq[2];
    aq[0] = *(const bf16x8*)(qkv + qrow + fq * 8);
    aq[1] = *(const bf16x8*)(qkv + qrow + 32 + fq * 8);

    __syncthreads();

    f32x4 sc[12] = {};
    #pragma unroll
    for (int nt = 0; nt < 12; ++nt) {
        #pragma unroll
        for (int ks = 0; ks < 2; ++ks) {
            bf16x8 bk = *(const bf16x8*)(Ks + (ks * 192 + nt * 16 + fr) * 32 + fq * 8);
            sc[nt] = __builtin_amdgcn_mfma_f32_16x16x32_bf16(aq[ks], bk, sc[nt], 0, 0, 0);
        }
    }

    float mx[4] = { -1e30f, -1e30f, -1e30f, -1e30f };
    #pragma unroll
    for (int nt = 0; nt < 12; ++nt) {
        const int jr = nt * 16 + fr;
        const int j  = i0 - 64 + jr;
        const bool jv = (j >= 0) && (j < S_);
        #pragma unroll
        for (int r = 0; r < 4; ++r) {
            const int ir = wq0 + fq * 4 + r + 64;
            const int dd = ir - jr;
            const bool v = jv && (dd <= WIN_) && (dd >= -WIN_);
            sc[nt][r] = v ? sc[nt][r] * 0.125f : -1e30f;
            mx[r] = fmaxf(mx[r], sc[nt][r]);
        }
    }
    #pragma unroll
    for (int r = 0; r < 4; ++r)
        #pragma unroll
        for (int off = 1; off < 16; off <<= 1)
            mx[r] = fmaxf(mx[r], __shfl_xor(mx[r], off, 64));

    float sm[4] = { 0.f, 0.f, 0.f, 0.f };
    #pragma unroll
    for (int nt = 0; nt < 12; ++nt)
        #pragma unroll
        for (int r = 0; r < 4; ++r) {
            float e = __expf(sc[nt][r] - mx[r]);
            sc[nt][r] = e;
            sm[r] += e;
        }
    #pragma unroll
    for (int r = 0; r < 4; ++r) {
        #pragma unroll
        for (int off = 1; off < 16; off <<= 1)
            sm[r] += __shfl_xor(sm[r], off, 64);
        sm[r] = 1.0f / sm[r];
    }

    __syncthreads();

    __bf16* Pw = Ks + w * 3072;
    #pragma unroll
    for (int nt = 0; nt < 12; ++nt) {
        const int ks = nt >> 1, kk = (nt & 1) * 16 + fr;
        #pragma unroll
        for (int r = 0; r < 4; ++r)
            Pw[(ks * 16 + fq * 4 + r) * 32 + kk] = (__bf16)(sc[nt][r] * sm[r]);
    }

    f32x4 oacc[4] = {};
    #pragma unroll
    for (int ks = 0; ks < 6; ++ks) {
        bf16x8 ap = *(const bf16x8*)(Pw + (ks * 16 + fr) * 32 + fq * 8);
        #pragma unroll
        for (int nt2 = 0; nt2 < 4; ++nt2) {
            bf16x8 bv = *(const bf16x8*)(Vts + (ks * 64 + nt2 * 16 + fr) * 32 + fq * 8);
            oacc[nt2] = __builtin_amdgcn_mfma_f32_16x16x32_bf16(ap, bv, oacc[nt2], 0, 0, 0);
        }
    }

    // O via per-wave LDS bounce (reuse Pw region) -> coalesced 128-B rows
    #pragma unroll
    for (int nt2 = 0; nt2 < 4; ++nt2)
        #pragma unroll
        for (int r = 0; r < 4; ++r)
            Pw[(fq * 4 + r) * 68 + nt2 * 16 + fr] = (__bf16)oacc[nt2][r];
    #pragma unroll
    for (int p = 0; p < 2; ++p) {
        const int q = p * 8 + (lane >> 3), ch = lane & 7;
        bf16x8 vv = *(const bf16x8*)(Pw + q * 68 + ch * 8);
        *(bf16x8*)(outb + ((size_t)b * S_ + i0 + wq0 + q) * D_ + h * HD_ + ch * 8) = vv;
    }
}

// ---------------------------------------------------------------------------
extern "C" void kernel_launch(void* const* d_in, const int* in_sizes, int n_in,
                              void* d_out, int out_size, void* d_ws, size_t ws_size,
                              hipStream_t stream) {
    const float* hs   = (const float*)d_in[0];
    const float* wqkv = (const float*)d_in[1];
    const float* wo   = (const float*)d_in[2];
    const int*   pos  = (const int*)d_in[4];
    float* out = (float*)d_out;

    __bf16* base    = (__bf16*)d_ws;
    __bf16* hs_bf   = base;                          // 3,145,728
    __bf16* wqkv_bf = hs_bf + NHS;                   // 1,769,472
    __bf16* wo_bf   = wqkv_bf + NWQ;                 //   589,824
    __bf16* qkv     = wo_bf + NWO;                   // 4096*1536
    __bf16* vt      = qkv + (size_t)(B_ * S_) * (2 * D_);   // 2*12*64*2048
    __bf16* attn_bf = vt + (size_t)B_ * H_ * HD_ * S_;      // 4096*768

    // 1) fp32 -> bf16
    to_bf16_3<<<(NHS + NWQ + NWO) / 1024, 256, 0, stream>>>(
        hs, wqkv, wo, hs_bf, wqkv_bf, wo_bf);

    // 2) qkv = hs @ Wqkv^T  (RoPE fused -> qkv bf16; v -> vt transposed)
    //    register-direct fragments, scratch-free, 2304 waves all resident
    gemm_r<1><<<dim3(64 * (3 * D_ / 256)), 256, 0, stream>>>(
        hs_bf, wqkv_bf, nullptr, qkv, vt, pos, B_ * S_, 3 * D_, D_);

    // 3) banded MFMA attention
    attn_mfma<<<dim3(S_ / 64, H_, B_), 256, 0, stream>>>(qkv, vt, attn_bf);

    // 4) out = attn @ Wo^T (fp32 out, coalesced epilogue)
    gemm_r<0><<<dim3(64 * (D_ / 256)), 256, 0, stream>>>(
        attn_bf, wo_bf, out, nullptr, nullptr, nullptr, B_ * S_, D_, D_);
}

// Round 5
// 135.351 us; speedup vs baseline: 1.4297x; 1.4080x over previous
//
#include <hip/hip_runtime.h>
#include <hip/hip_bf16.h>
#include <cmath>

#define B_   2
#define S_   2048
#define D_   768
#define H_   12
#define HD_  64
#define WIN_ 64

typedef __bf16 bf16x8 __attribute__((ext_vector_type(8)));
typedef __bf16 bf16x4 __attribute__((ext_vector_type(4)));
typedef float  f32x4  __attribute__((ext_vector_type(4)));
typedef unsigned int u32;

__device__ __forceinline__ void async_ld16(const void* g, void* l) {
    __builtin_amdgcn_global_load_lds(
        (__attribute__((address_space(1))) void*)(size_t)g,
        (__attribute__((address_space(3))) void*)(u32)(size_t)l,
        16, 0, 0);
}

// ---------------------------------------------------------------------------
// fp32 -> bf16 convert for hs / Wqkv / Wo (one pass)
// ---------------------------------------------------------------------------
#define NHS (B_ * S_ * D_)        // 3145728
#define NWQ (3 * D_ * D_)         // 1769472
#define NWO (D_ * D_)             //  589824

__global__ __launch_bounds__(256) void to_bf16_3(const float* __restrict__ a,
                                                 const float* __restrict__ b,
                                                 const float* __restrict__ c,
                                                 __bf16* __restrict__ oa,
                                                 __bf16* __restrict__ ob,
                                                 __bf16* __restrict__ oc) {
    const int NA = NHS / 4, NB = NWQ / 4;
    int v = blockIdx.x * 256 + threadIdx.x;
    const float* src; __bf16* dst; int idx;
    if (v < NA)           { src = a; dst = oa; idx = v; }
    else if (v < NA + NB) { src = b; dst = ob; idx = v - NA; }
    else                  { src = c; dst = oc; idx = v - NA - NB; }
    float4 x = ((const float4*)src)[idx];
    bf16x4 y = { (__bf16)x.x, (__bf16)x.y, (__bf16)x.z, (__bf16)x.w };
    *(bf16x4*)(dst + (size_t)idx * 4) = y;
}

// ---------------------------------------------------------------------------
// GEMM, round-16: block-cooperative 128x128 tile, 2-phase double-buffered
// LDS staging (T3-minimum).  Rounds 1-4 post-mortem: every per-wave-private
// scheme (gload_lds w/ runtime buf, register frags w/ lambdas, w/ macros)
// compiled to ~7200 cyc/K-iter = 8 serial load round-trips; both gemms
// pinned at the single-wave critical path.  Fix: the m97-family structure
// the HW guide verified overlaps correctly from plain HIP:
//  - 4 waves cooperatively stage A[128][32] + B[128][32] per K-step via
//    global_load_lds into STATICALLY DISTINCT buffers sA0/sB0 vs sA1/sB1
//    (provably disjoint -> ds_reads of cur buf carry no wait against the
//    in-flight DMA of next buf);
//  - ONE __syncthreads per K-step: its implicit vmcnt(0) lands the NEXT
//    tile after the whole compute phase has covered its latency;
//  - verified chunk-permute staging / sw-read swizzle (same mod-4 algebra
//    as rounds 0-1, rows extended to 128).
// Wave w owns quadrant (wr,wc) = (w>>1, w&1), 64x64, acc[4][4] in AGPRs.
// Grid: 32 m-tiles x N/128 n-tiles, m-fastest (XCD A-panel partitioning).
// Epilogues: round-1-verified, split into 32-row passes in per-wave 8 KB
// LDS regions (overlaying the staging buffers after the final barrier).
// MODE 0: fp32 C.  MODE 1: fused RoPE -> qkv bf16 (n<1536); v -> vt bf16^T.
// ---------------------------------------------------------------------------
#define GSTAGE(DA, DB, kk)                                                    \
    { const int k0_ = (kk) << 5;                                              \
      _Pragma("unroll")                                                       \
      for (int i_ = 0; i_ < 2; ++i_) {                                        \
          const int c_ = i_ * 256 + tid;                                      \
          const int row_ = c_ >> 2;                                           \
          const int cc_ = ((c_ & 3) - (row_ >> 1)) & 3;                       \
          async_ld16(A  + (size_t)(m0 + row_) * K + k0_ + cc_ * 8, (DA) + c_ * 8); \
          async_ld16(Bw + (size_t)(n0 + row_) * K + k0_ + cc_ * 8, (DB) + c_ * 8); \
      } }

#define TCOMP(SA, SB)                                                         \
    { bf16x8 af_[4], bf_[4];                                                  \
      _Pragma("unroll")                                                       \
      for (int t_ = 0; t_ < 4; ++t_) {                                        \
          af_[t_] = *(const bf16x8*)((SA) + (wr64 + t_ * 16 + fr) * 32 + sw * 8); \
          bf_[t_] = *(const bf16x8*)((SB) + (wc64 + t_ * 16 + fr) * 32 + sw * 8); \
      }                                                                       \
      _Pragma("unroll")                                                       \
      for (int ti_ = 0; ti_ < 4; ++ti_)                                       \
          _Pragma("unroll")                                                   \
          for (int tj_ = 0; tj_ < 4; ++tj_)                                   \
              acc[ti_][tj_] = __builtin_amdgcn_mfma_f32_16x16x32_bf16(        \
                  af_[ti_], bf_[tj_], acc[ti_][tj_], 0, 0, 0); }

template <int MODE>
__global__ __launch_bounds__(256) void gemm_t(const __bf16* __restrict__ A,
                                              const __bf16* __restrict__ Bw,
                                              float* __restrict__ C,
                                              __bf16* __restrict__ qkv,
                                              __bf16* __restrict__ vt,
                                              const int* __restrict__ pos,
                                              int M, int N, int K) {
    __shared__ __attribute__((aligned(16))) __bf16 sA0[4096];   // 128x32
    __shared__ __attribute__((aligned(16))) __bf16 sB0[4096];
    __shared__ __attribute__((aligned(16))) __bf16 sA1[4096];
    __shared__ __attribute__((aligned(16))) __bf16 sB1[4096];

    const int tid  = threadIdx.x;
    const int w    = tid >> 6;
    const int lane = tid & 63;
    const int id = blockIdx.x;
    const int m0 = (id & 31) << 7;          // m fastest: XCD partitioning
    const int n0 = (id >> 5) << 7;
    const int fr = lane & 15, fq = lane >> 4;
    const int sw = (fq + (fr >> 1)) & 3;    // swizzled chunk-in-row (verified)
    const int wr64 = (w >> 1) * 64, wc64 = (w & 1) * 64;

    f32x4 acc[4][4] = {};

    const int nkw = K >> 5;                 // 24 (even)

    GSTAGE(sA0, sB0, 0)
    __syncthreads();                        // drains tile-0 DMA
    int t = 0;
    for (; t + 2 < nkw; t += 2) {
        GSTAGE(sA1, sB1, t + 1)             // issue next tile (odd)
        TCOMP(sA0, sB0)                     // compute even tile
        __syncthreads();                    // implicit vmcnt(0): odd tile landed
        GSTAGE(sA0, sB0, t + 2)             // issue next tile (even)
        TCOMP(sA1, sB1)                     // compute odd tile
        __syncthreads();
    }
    GSTAGE(sA1, sB1, nkw - 1)
    TCOMP(sA0, sB0)                         // tile nkw-2
    __syncthreads();
    TCOMP(sA1, sB1)                         // tile nkw-1
    __syncthreads();                        // all LDS reads retired -> overlay

    // ---- per-wave epilogue in private 8 KB region (overlays staging) ----
    __bf16* eW = (w == 0) ? sA0 : (w == 1) ? sB0 : (w == 2) ? sA1 : sB1;
    const int mm0 = m0 + wr64, nn0 = n0 + wc64;

    if (MODE == 0) {
        float* eL = (float*)eW;             // [32][64] fp32 = 8192 B, 2 passes
        #pragma unroll
        for (int half = 0; half < 2; ++half) {
            #pragma unroll
            for (int ti = 0; ti < 2; ++ti)
                #pragma unroll
                for (int tj = 0; tj < 4; ++tj)
                    #pragma unroll
                    for (int r = 0; r < 4; ++r)
                        eL[(ti * 16 + fq * 4 + r) * 64 + tj * 16 + fr] =
                            acc[half * 2 + ti][tj][r];
            #pragma unroll
            for (int p = 0; p < 8; ++p) {
                const int rc = p * 4 + (lane >> 4), ch = lane & 15;
                f32x4 vv = *(const f32x4*)(eL + rc * 64 + ch * 4);
                *(f32x4*)(C + (size_t)(mm0 + half * 32 + rc) * N + nn0 + ch * 4) = vv;
            }
        }
    } else if (nn0 < 2 * D_) {
        // fused RoPE on fp32 acc, then bf16 coalesced store (2 passes)
        const float invf0 = __powf(10000.0f, -(float)fr * (1.0f / 32.0f));
        const float invf1 = __powf(10000.0f, -(float)(16 + fr) * (1.0f / 32.0f));
        #pragma unroll
        for (int ti = 0; ti < 4; ++ti)
            #pragma unroll
            for (int r = 0; r < 4; ++r) {
                const int row = mm0 + ti * 16 + fq * 4 + r;
                const float p = (float)pos[row];
                float s0, c0, s1, c1;
                __sincosf(p * invf0, &s0, &c0);
                __sincosf(p * invf1, &s1, &c1);
                const float x0 = acc[ti][0][r], x1 = acc[ti][2][r];
                acc[ti][0][r] = x0 * c0 - x1 * s0;
                acc[ti][2][r] = x1 * c0 + x0 * s0;
                const float y0 = acc[ti][1][r], y1 = acc[ti][3][r];
                acc[ti][1][r] = y0 * c1 - y1 * s1;
                acc[ti][3][r] = y1 * c1 + y0 * s1;
            }
        __bf16* eL = eW;                    // [32][68] bf16 = 4352 B, 2 passes
        #pragma unroll
        for (int half = 0; half < 2; ++half) {
            #pragma unroll
            for (int ti = 0; ti < 2; ++ti)
                #pragma unroll
                for (int tj = 0; tj < 4; ++tj)
                    #pragma unroll
                    for (int r = 0; r < 4; ++r)
                        eL[(ti * 16 + fq * 4 + r) * 68 + tj * 16 + fr] =
                            (__bf16)acc[half * 2 + ti][tj][r];
            #pragma unroll
            for (int p = 0; p < 4; ++p) {
                const int rq = p * 8 + (lane >> 3), ch = lane & 7;
                bf16x8 vv = *(const bf16x8*)(eL + rq * 68 + ch * 8);
                *(bf16x8*)(qkv + (size_t)(mm0 + half * 32 + rq) * (2 * D_) + nn0 + ch * 8) = vv;
            }
        }
    } else {
        // v -> vt[b][h][d][token], transposed in LDS, 2 passes over d-halves
        const int h = (nn0 - 2 * D_) >> 6;
        const int bb = mm0 >> 11, t0 = mm0 & (S_ - 1);
        __bf16* eL = eW;                    // [32 d][68 tok] bf16 = 4352 B
        const size_t vb = (size_t)((bb * H_ + h) * HD_) * S_ + t0;
        #pragma unroll
        for (int dh = 0; dh < 2; ++dh) {
            #pragma unroll
            for (int tj = 0; tj < 2; ++tj)
                #pragma unroll
                for (int ti = 0; ti < 4; ++ti)
                    #pragma unroll
                    for (int r = 0; r < 4; ++r)
                        eL[(tj * 16 + fr) * 68 + ti * 16 + fq * 4 + r] =
                            (__bf16)acc[ti][dh * 2 + tj][r];
            #pragma unroll
            for (int p = 0; p < 4; ++p) {
                const int d = p * 8 + (lane >> 3), ch = lane & 7;
                bf16x8 vv = *(const bf16x8*)(eL + d * 68 + ch * 8);
                *(bf16x8*)(vt + vb + (size_t)(dh * 32 + d) * S_ + ch * 8) = vv;
            }
        }
    }
}

// ---------------------------------------------------------------------------
// MFMA banded attention.  Block = 64 queries x (head, batch), 4 waves.
// LDS (48 KB): Ks [2][192][32] (24 KB, overlaid by P), Vts [6][64][32] (24 KB).
// Q frags direct from global.  O store bounced through LDS (coalesced 128-B).
// ---------------------------------------------------------------------------
__global__ __launch_bounds__(256) void attn_mfma(const __bf16* __restrict__ qkv,
                                                 const __bf16* __restrict__ vt,
                                                 __bf16* __restrict__ outb) {
    __shared__ __attribute__((aligned(16))) __bf16 smem[24576];  // 48 KB
    __bf16* Ks  = smem;
    __bf16* Vts = smem + 12288;

    const int i0  = blockIdx.x * 64;
    const int h   = blockIdx.y;
    const int b   = blockIdx.z;
    const int tid = threadIdx.x;
    const int w = tid >> 6, lane = tid & 63;
    const int fr = lane & 15, fq = lane >> 4;
    const int wq0 = w * 16;

    #pragma unroll
    for (int i = 0; i < 6; ++i) {
        int c = i * 256 + tid;
        int ks = (i >= 3);
        int rem = c - ks * 768;
        int cc = rem & 3, row = rem >> 2;
        int j = i0 - 64 + row; j = min(max(j, 0), S_ - 1);   // clamped; masked later
        async_ld16(qkv + ((size_t)b * S_ + j) * (2 * D_) + D_ + h * HD_ + ks * 32 + cc * 8,
                   Ks + c * 8);
    }
    const size_t vbase = (size_t)((b * H_ + h) * HD_) * S_;
    #pragma unroll
    for (int i = 0; i < 6; ++i) {
        int c = i * 256 + tid;
        int ks = c >> 8, rem = c & 255, d = rem >> 2, cc = rem & 3;
        int key = i0 - 64 + ks * 32 + cc * 8;
        key = min(max(key, 0), S_ - 8);                      // clamped; masked later
        async_ld16(vt + vbase + (size_t)d * S_ + key, Vts + c * 8);
    }

    const size_t qrow = ((size_t)b * S_ + i0 + wq0 + fr) * (2 * D_) + h * HD_;
    bf16x8 aq[2];
    aq[0] = *(const bf16x8*)(qkv + qrow + fq * 8);
    aq[1] = *(const bf16x8*)(qkv + qrow + 32 + fq * 8);

    __syncthreads();

    f32x4 sc[12] = {};
    #pragma unroll
    for (int nt = 0; nt < 12; ++nt) {
        #pragma unroll
        for (int ks = 0; ks < 2; ++ks) {
            bf16x8 bk = *(const bf16x8*)(Ks + (ks * 192 + nt * 16 + fr) * 32 + fq * 8);
            sc[nt] = __builtin_amdgcn_mfma_f32_16x16x32_bf16(aq[ks], bk, sc[nt], 0, 0, 0);
        }
    }

    float mx[4] = { -1e30f, -1e30f, -1e30f, -1e30f };
    #pragma unroll
    for (int nt = 0; nt < 12; ++nt) {
        const int jr = nt * 16 + fr;
        const int j  = i0 - 64 + jr;
        const bool jv = (j >= 0) && (j < S_);
        #pragma unroll
        for (int r = 0; r < 4; ++r) {
            const int ir = wq0 + fq * 4 + r + 64;
            const int dd = ir - jr;
            const bool v = jv && (dd <= WIN_) && (dd >= -WIN_);
            sc[nt][r] = v ? sc[nt][r] * 0.125f : -1e30f;
            mx[r] = fmaxf(mx[r], sc[nt][r]);
        }
    }
    #pragma unroll
    for (int r = 0; r < 4; ++r)
        #pragma unroll
        for (int off = 1; off < 16; off <<= 1)
            mx[r] = fmaxf(mx[r], __shfl_xor(mx[r], off, 64));

    float sm[4] = { 0.f, 0.f, 0.f, 0.f };
    #pragma unroll
    for (int nt = 0; nt < 12; ++nt)
        #pragma unroll
        for (int r = 0; r < 4; ++r) {
            float e = __expf(sc[nt][r] - mx[r]);
            sc[nt][r] = e;
            sm[r] += e;
        }
    #pragma unroll
    for (int r = 0; r < 4; ++r) {
        #pragma unroll
        for (int off = 1; off < 16; off <<= 1)
            sm[r] += __shfl_xor(sm[r], off, 64);
        sm[r] = 1.0f / sm[r];
    }

    __syncthreads();

    __bf16* Pw = Ks + w * 3072;
    #pragma unroll
    for (int nt = 0; nt < 12; ++nt) {
        const int ks = nt >> 1, kk = (nt & 1) * 16 + fr;
        #pragma unroll
        for (int r = 0; r < 4; ++r)
            Pw[(ks * 16 + fq * 4 + r) * 32 + kk] = (__bf16)(sc[nt][r] * sm[r]);
    }

    f32x4 oacc[4] = {};
    #pragma unroll
    for (int ks = 0; ks < 6; ++ks) {
        bf16x8 ap = *(const bf16x8*)(Pw + (ks * 16 + fr) * 32 + fq * 8);
        #pragma unroll
        for (int nt2 = 0; nt2 < 4; ++nt2) {
            bf16x8 bv = *(const bf16x8*)(Vts + (ks * 64 + nt2 * 16 + fr) * 32 + fq * 8);
            oacc[nt2] = __builtin_amdgcn_mfma_f32_16x16x32_bf16(ap, bv, oacc[nt2], 0, 0, 0);
        }
    }

    // O via per-wave LDS bounce (reuse Pw region) -> coalesced 128-B rows
    #pragma unroll
    for (int nt2 = 0; nt2 < 4; ++nt2)
        #pragma unroll
        for (int r = 0; r < 4; ++r)
            Pw[(fq * 4 + r) * 68 + nt2 * 16 + fr] = (__bf16)oacc[nt2][r];
    #pragma unroll
    for (int p = 0; p < 2; ++p) {
        const int q = p * 8 + (lane >> 3), ch = lane & 7;
        bf16x8 vv = *(const bf16x8*)(Pw + q * 68 + ch * 8);
        *(bf16x8*)(outb + ((size_t)b * S_ + i0 + wq0 + q) * D_ + h * HD_ + ch * 8) = vv;
    }
}

// ---------------------------------------------------------------------------
extern "C" void kernel_launch(void* const* d_in, const int* in_sizes, int n_in,
                              void* d_out, int out_size, void* d_ws, size_t ws_size,
                              hipStream_t stream) {
    const float* hs   = (const float*)d_in[0];
    const float* wqkv = (const float*)d_in[1];
    const float* wo   = (const float*)d_in[2];
    const int*   pos  = (const int*)d_in[4];
    float* out = (float*)d_out;

    __bf16* base    = (__bf16*)d_ws;
    __bf16* hs_bf   = base;                          // 3,145,728
    __bf16* wqkv_bf = hs_bf + NHS;                   // 1,769,472
    __bf16* wo_bf   = wqkv_bf + NWQ;                 //   589,824
    __bf16* qkv     = wo_bf + NWO;                   // 4096*1536
    __bf16* vt      = qkv + (size_t)(B_ * S_) * (2 * D_);   // 2*12*64*2048
    __bf16* attn_bf = vt + (size_t)B_ * H_ * HD_ * S_;      // 4096*768

    // 1) fp32 -> bf16
    to_bf16_3<<<(NHS + NWQ + NWO) / 1024, 256, 0, stream>>>(
        hs, wqkv, wo, hs_bf, wqkv_bf, wo_bf);

    // 2) qkv = hs @ Wqkv^T  (RoPE fused -> qkv bf16; v -> vt transposed)
    //    block-cooperative 128x128 tiles, 2-phase dbuf staging
    gemm_t<1><<<dim3(32 * (3 * D_ / 128)), 256, 0, stream>>>(
        hs_bf, wqkv_bf, nullptr, qkv, vt, pos, B_ * S_, 3 * D_, D_);

    // 3) banded MFMA attention
    attn_mfma<<<dim3(S_ / 64, H_, B_), 256, 0, stream>>>(qkv, vt, attn_bf);

    // 4) out = attn @ Wo^T (fp32 out, coalesced epilogue)
    gemm_t<0><<<dim3(32 * (D_ / 128)), 256, 0, stream>>>(
        attn_bf, wo_bf, out, nullptr, nullptr, nullptr, B_ * S_, D_, D_);
}